// Round 5
// baseline (110.738 us; speedup 1.0000x reference)
//
#include <hip/hip_runtime.h>

// LengthRegulator: out[b, t, :] = phoneme[b, idx[b,t], :]
// idx[b,t] = searchsorted(inclusive_cumsum(durations[b]), t, side='right').
// Shapes fixed: B=16, N=256, D=512, T=2048. fp32 in/out.
//
// R4 -> R5: MEASUREMENT PROBE. Kernel reverted to R2 (plain float4 stores,
// register wave-scan). kernel_launch launches it 3x (idempotent) so
// kernel-proper time = (dur_R5 - dur_R4)/2, isolating it from the ~55 us
// of harness poison/restore fills that dominate the timed window.

typedef float f4 __attribute__((ext_vector_type(4)));

constexpr int B = 16;
constexpr int N = 256;    // tokens per batch (== block size)
constexpr int D = 512;    // feature dim -> 128 f4 per row
constexpr int T = 2048;   // output frames per batch

constexpr int BLOCKS_PER_B = 128;                  // blocks per batch
constexpr int FPB = T / BLOCKS_PER_B;              // 16 frames per block
constexpr int VPR = D / 4;                         // 128 f4 per row

__global__ __launch_bounds__(256) void lenreg_kernel(
    const f4* __restrict__ ph4,       // (B, N, D/4)
    const int* __restrict__ durations,// (B, N)
    f4* __restrict__ out4)            // (B, T, D/4)
{
    __shared__ int ends[N];     // inclusive cumsum of durations[b,:]
    __shared__ int wsum[4];     // per-wave totals
    __shared__ int fidx[FPB];   // token index per frame in this chunk

    const int b     = blockIdx.x >> 7;        // / BLOCKS_PER_B
    const int chunk = blockIdx.x & (BLOCKS_PER_B - 1);
    const int tid   = threadIdx.x;
    const int lane  = tid & 63;
    const int wid   = tid >> 6;

    // --- (a) inclusive prefix sum: register wave-scan + cross-wave combine
    int v = durations[b * N + tid];
    #pragma unroll
    for (int off = 1; off < 64; off <<= 1) {
        int u = __shfl_up(v, off, 64);
        if (lane >= off) v += u;
    }
    if (lane == 63) wsum[wid] = v;
    __syncthreads();
    int prefix = 0;
    #pragma unroll
    for (int w = 0; w < 3; ++w)
        if (w < wid) prefix += wsum[w];
    ends[tid] = v + prefix;
    __syncthreads();

    // --- (b) token index for each of this block's 16 frames
    const int f0 = chunk * FPB;
    if (tid < FPB) {
        const int t = f0 + tid;
        int lo = 0, hi = N;         // first n with ends[n] > t
        while (lo < hi) {
            const int mid = (lo + hi) >> 1;
            if (ends[mid] > t) hi = mid; else lo = mid + 1;
        }
        fidx[tid] = (lo < N - 1) ? lo : (N - 1);
    }
    __syncthreads();

    // --- (c) stream 16 rows, 2 rows/iter, coalesced float4
    const int l    = tid & (VPR - 1);   // 0..127
    const int half = tid >> 7;          // 0 or 1
    const int outbase = (b * T + f0) * VPR;   // fits int32
    const int phbase  = b * N * VPR;
    #pragma unroll
    for (int i = 0; i < FPB / 2; ++i) {
        const int r     = i * 2 + half;
        const int token = fidx[r];
        out4[outbase + r * VPR + l] = ph4[phbase + token * VPR + l];
    }
}

extern "C" void kernel_launch(void* const* d_in, const int* in_sizes, int n_in,
                              void* d_out, int out_size, void* d_ws, size_t ws_size,
                              hipStream_t stream) {
    const f4*  phoneme   = (const f4*)d_in[0];
    const int* durations = (const int*)d_in[1];
    f4*        out       = (f4*)d_out;

    // 3 identical idempotent launches: timing probe to isolate kernel time
    // from the fixed harness poison/restore overhead in the measured window.
    lenreg_kernel<<<B * BLOCKS_PER_B, 256, 0, stream>>>(phoneme, durations, out);
    lenreg_kernel<<<B * BLOCKS_PER_B, 256, 0, stream>>>(phoneme, durations, out);
    lenreg_kernel<<<B * BLOCKS_PER_B, 256, 0, stream>>>(phoneme, durations, out);
}

// Round 6
// 85.017 us; speedup vs baseline: 1.3025x; 1.3025x over previous
//
#include <hip/hip_runtime.h>

// LengthRegulator: out[b, t, :] = phoneme[b, idx[b,t], :]
// idx[b,t] = searchsorted(inclusive_cumsum(durations[b]), t, side='right').
// Shapes fixed: B=16, N=256, D=512, T=2048. fp32 in/out.
//
// FINAL (R6 = R2): single launch, register __shfl_up wave-scan (3 barriers),
// fully coalesced float4 row streaming (each block writes one contiguous
// 32 KB span). Measured kernel-proper time ~13.8 us (R5 3x-launch probe:
// (110.7-83.1)/2), vs ~11-13 us memory roofline for 67 MB writes + 17 MB
// reads at the 6.1-6.3 TB/s achievable ceiling -> at roofline. The ~69 us
// remainder of the timed window is fixed harness poison/restore overhead
// (visible as fillBufferAligned dispatches dominating the profile).

typedef float f4 __attribute__((ext_vector_type(4)));

constexpr int B = 16;
constexpr int N = 256;    // tokens per batch (== block size)
constexpr int D = 512;    // feature dim -> 128 f4 per row
constexpr int T = 2048;   // output frames per batch

constexpr int BLOCKS_PER_B = 128;                  // blocks per batch
constexpr int FPB = T / BLOCKS_PER_B;              // 16 frames per block
constexpr int VPR = D / 4;                         // 128 f4 per row

__global__ __launch_bounds__(256) void lenreg_kernel(
    const f4* __restrict__ ph4,       // (B, N, D/4)
    const int* __restrict__ durations,// (B, N)
    f4* __restrict__ out4)            // (B, T, D/4)
{
    __shared__ int ends[N];     // inclusive cumsum of durations[b,:]
    __shared__ int wsum[4];     // per-wave totals
    __shared__ int fidx[FPB];   // token index per frame in this chunk

    const int b     = blockIdx.x >> 7;        // / BLOCKS_PER_B
    const int chunk = blockIdx.x & (BLOCKS_PER_B - 1);
    const int tid   = threadIdx.x;
    const int lane  = tid & 63;
    const int wid   = tid >> 6;

    // --- (a) inclusive prefix sum: register wave-scan + cross-wave combine
    int v = durations[b * N + tid];
    #pragma unroll
    for (int off = 1; off < 64; off <<= 1) {
        int u = __shfl_up(v, off, 64);
        if (lane >= off) v += u;
    }
    if (lane == 63) wsum[wid] = v;
    __syncthreads();
    int prefix = 0;
    #pragma unroll
    for (int w = 0; w < 3; ++w)
        if (w < wid) prefix += wsum[w];
    ends[tid] = v + prefix;
    __syncthreads();

    // --- (b) token index for each of this block's 16 frames
    const int f0 = chunk * FPB;
    if (tid < FPB) {
        const int t = f0 + tid;
        int lo = 0, hi = N;         // first n with ends[n] > t
        while (lo < hi) {
            const int mid = (lo + hi) >> 1;
            if (ends[mid] > t) hi = mid; else lo = mid + 1;
        }
        fidx[tid] = (lo < N - 1) ? lo : (N - 1);
    }
    __syncthreads();

    // --- (c) stream 16 rows, 2 rows/iter, coalesced float4
    const int l    = tid & (VPR - 1);   // 0..127
    const int half = tid >> 7;          // 0 or 1
    const int outbase = (b * T + f0) * VPR;   // fits int32
    const int phbase  = b * N * VPR;
    #pragma unroll
    for (int i = 0; i < FPB / 2; ++i) {
        const int r     = i * 2 + half;
        const int token = fidx[r];
        out4[outbase + r * VPR + l] = ph4[phbase + token * VPR + l];
    }
}

extern "C" void kernel_launch(void* const* d_in, const int* in_sizes, int n_in,
                              void* d_out, int out_size, void* d_ws, size_t ws_size,
                              hipStream_t stream) {
    const f4*  phoneme   = (const f4*)d_in[0];
    const int* durations = (const int*)d_in[1];
    f4*        out       = (f4*)d_out;

    lenreg_kernel<<<B * BLOCKS_PER_B, 256, 0, stream>>>(phoneme, durations, out);
}